// Round 1
// 328.331 us; speedup vs baseline: 2.1175x; 2.1175x over previous
//
#include <hip/hip_runtime.h>
#include <hip/hip_bf16.h>
#include <math.h>

// Problem constants
#define B_    32
#define FIN   16
#define LIN   8192
#define LAT   64
#define L1V   8190      // length after k=3 valid conv
#define PN    200
#define PLEN  16
#define LOV   8175      // L1V - 16 + 1
#define NCLS  10
#define EPSV  1e-4f
#define MD0   320       // f32 offset of min_distances in d_out
#define CHK   256       // positions per block
#define WIN   272       // window slots (CHK + 16)
#define FST   68        // fwin row stride in u16 (136 B: 2-way bank aliasing = free)
#define NPT   7         // proto tiles of 32 (200 padded to 224)
#define NFRAG (NPT * 16 * 4 * 64)   // 28672 pre-packed B-fragments

typedef unsigned short u16;
typedef unsigned int   u32;
typedef short s16x8 __attribute__((ext_vector_type(8)));   // 8 bf16 (4 VGPRs)
typedef float f32x16 __attribute__((ext_vector_type(16))); // 32x32 MFMA accumulator

union FragU { uint2 u2[2]; s16x8 v; };

__device__ __forceinline__ u16 vf2b(float f) {
    union { float f; u32 u; } v; v.f = f;
    u32 u = v.u;
    return (u16)((u + 0x7fffu + ((u >> 16) & 1u)) >> 16);   // RNE
}

// K0: wsm = FLT_MAX bits; p2g = ||proto||^2; waT = wa transposed [c][o];
//     pk = protos pre-packed as per-lane MFMA B-fragments:
//     frag f = ((p7*16 + tap)*4 + cs)*64 + lane holds 8 bf16:
//     proto (p7*32 + (lane&31)), channels cs*16 + (lane>>5)*8 + j, tap.
__global__ void k_init(const float* __restrict__ pt, const float* __restrict__ wa,
                       u32* __restrict__ wsm, float* __restrict__ p2g,
                       float* __restrict__ waT, u16* __restrict__ pk) {
    const int tid = blockIdx.x * 256 + threadIdx.x;
    const int N   = gridDim.x * 256;

    for (int j = tid; j < B_ * PN; j += N) wsm[j] = 0x7f7fffffu;

    for (int j = tid; j < LAT * LAT; j += N)
        waT[j] = wa[(j & 63) * LAT + (j >> 6)];

    for (int p = tid; p < 224; p += N) {
        float s = 0.f;
        if (p < PN) {
            const float4* pr = (const float4*)(pt + (size_t)p * (LAT * PLEN));
            #pragma unroll 4
            for (int j = 0; j < 256; ++j) {
                float4 v = pr[j];
                s += v.x * v.x + v.y * v.y + v.z * v.z + v.w * v.w;
            }
        }
        p2g[p] = s;
    }

    for (int f = tid; f < NFRAG; f += N) {
        const int lane = f & 63;
        const int cs   = (f >> 6) & 3;
        const int tap  = (f >> 8) & 15;
        const int p7   = f >> 12;
        const int gp   = p7 * 32 + (lane & 31);
        const int chb  = cs * 16 + (lane >> 5) * 8;
        s16x8 v;
        if (gp < PN) {
            const float* src = pt + (size_t)gp * (LAT * PLEN) + (size_t)chb * PLEN + tap;
            #pragma unroll
            for (int j = 0; j < 8; ++j) v[j] = (short)vf2b(src[j * PLEN]);
        } else {
            #pragma unroll
            for (int j = 0; j < 8; ++j) v[j] = 0;
        }
        *(s16x8*)(pk + (size_t)f * 8) = v;
    }
}

// Fused encoder+addon for one position -> fwin POSITION-MAJOR bf16 [slot][64ch] + gwin f32.
// f1 chain split 4-way (f32 FMA is not reassociable at -O3: 48x4cy serial otherwise);
// addon weights read from pre-transposed waT (contiguous 256 B per channel).
__device__ __forceinline__ void enc_pos(int pos, int slot,
                                        const float* __restrict__ xb,
                                        const float* __restrict__ we,
                                        const float* __restrict__ waT,
                                        u32* __restrict__ fw32,
                                        float* __restrict__ gwin) {
    float acc[LAT];
    #pragma unroll
    for (int o = 0; o < LAT; ++o) acc[o] = 0.f;
    if (pos < L1V) {
        float xw[FIN * 3];
        #pragma unroll
        for (int c2 = 0; c2 < FIN; ++c2) {
            xw[c2 * 3 + 0] = xb[(size_t)c2 * LIN + pos + 0];
            xw[c2 * 3 + 1] = xb[(size_t)c2 * LIN + pos + 1];
            xw[c2 * 3 + 2] = xb[(size_t)c2 * LIN + pos + 2];
        }
        #pragma unroll 1
        for (int c = 0; c < LAT; ++c) {
            const float* w = we + c * 48;        // uniform -> s_loads
            float s0 = 0.f, s1 = 0.f, s2 = 0.f, s3 = 0.f;
            #pragma unroll
            for (int q = 0; q < 12; ++q) {
                s0 += xw[q]      * w[q];
                s1 += xw[q + 12] * w[q + 12];
                s2 += xw[q + 24] * w[q + 24];
                s3 += xw[q + 36] * w[q + 36];
            }
            float f1 = fmaxf((s0 + s1) + (s2 + s3), 0.f);
            const float* wc = waT + c * LAT;     // uniform, contiguous
            #pragma unroll
            for (int o = 0; o < LAT; ++o)
                acc[o] += f1 * wc[o];
        }
    }
    float gs = 0.f;
    #pragma unroll
    for (int o2 = 0; o2 < 32; ++o2) {
        float r0 = fmaxf(acc[2 * o2], 0.f);
        float r1 = fmaxf(acc[2 * o2 + 1], 0.f);
        fw32[slot * (FST / 2) + o2] = ((u32)vf2b(r1) << 16) | (u32)vf2b(r0);
        gs += r0 * r0 + r1 * r1;                 // s stays f32-exact
    }
    gwin[slot] = gs;
}

// K1: block = (chunk of 256 positions, batch). Encoder once into LDS (position-major),
// then tap-decomposed MFMA GEMM with B-fragments loaded DIRECTLY from pre-packed
// global memory (L2-resident): no proto staging, no barriers in the MFMA phase.
// LDS 39.1 KB -> 4 blocks/CU; whole 1024-block grid co-resident.
__global__ void __launch_bounds__(256, 4) k_dist(const float* __restrict__ x,
                                                 const float* __restrict__ we,
                                                 const float* __restrict__ waT,
                                                 const u16* __restrict__ pk,
                                                 u32* __restrict__ wsm,
                                                 const float* __restrict__ p2g) {
    __shared__ u16   fwin[WIN * FST];    // 36992 B, [slot][ch] bf16
    __shared__ float gwin[WIN];          // 1088 B
    __shared__ float sarr[CHK];          // 1024 B   (total 39104 B -> 4 blocks/CU)

    const int t  = threadIdx.x;
    const int ck = blockIdx.x;           // 0..31
    const int b  = blockIdx.y;           // 0..31
    const int base = ck * CHK;
    const float* xb = x + (size_t)b * FIN * LIN;

    // Phase 1: f2 window (272 slots), position-major bf16 + f32 g
    enc_pos(base + t, t, xb, we, waT, (u32*)fwin, gwin);
    if (t < 16) enc_pos(base + CHK + t, CHK + t, xb, we, waT, (u32*)fwin, gwin);
    __syncthreads();

    // Phase 2: sliding patch-norm (invalid positions poisoned with +huge)
    {
        float sv = 0.f;
        #pragma unroll
        for (int k = 0; k < PLEN; ++k) sv += gwin[t + k];
        sarr[t] = (base + t < LOV) ? sv : 3.0e38f;
    }
    __syncthreads();

    const int lane = t & 63;
    const int wv   = t >> 6;             // wave owns positions [wv*64, wv*64+64)
    const int m    = lane & 31;
    const int half = lane >> 5;
    const int koff = half * 8;           // k-chunk within 16-channel MFMA step

    #pragma unroll 1
    for (int p7 = 0; p7 < NPT; ++p7) {
        f32x16 acc0, acc1;
        #pragma unroll
        for (int i = 0; i < 16; ++i) { acc0[i] = 0.f; acc1[i] = 0.f; }

        const u16* pkb = pk + (size_t)p7 * (16 * 4 * 64 * 8) + (size_t)lane * 8;

        #pragma unroll 2
        for (int tap = 0; tap < 16; ++tap) {
            #pragma unroll
            for (int cs = 0; cs < 4; ++cs) {
                FragU bF, a0, a1;
                bF.v = *(const s16x8*)(pkb + (size_t)(tap * 4 + cs) * 64 * 8);
                const int co = cs * 16 + koff;
                const u16* ap = &fwin[(wv * 64 + m + tap) * FST + co];
                a0.u2[0] = *(const uint2*)ap; a0.u2[1] = *(const uint2*)(ap + 4);
                const u16* aq = ap + 32 * FST;
                a1.u2[0] = *(const uint2*)aq; a1.u2[1] = *(const uint2*)(aq + 4);
                acc0 = __builtin_amdgcn_mfma_f32_32x32x16_bf16(a0.v, bF.v, acc0, 0, 0, 0);
                acc1 = __builtin_amdgcn_mfma_f32_32x32x16_bf16(a1.v, bF.v, acc1, 0, 0, 0);
            }
        }

        // epilogue: d = s[pos] - 2*xp + p2[proto]; min over this wave's 64 positions
        // C layout (verified m74/m101): col = lane&31, row = (reg&3) + 8*(reg>>2) + 4*(lane>>5)
        const float p2v = p2g[p7 * 32 + m];
        float dmin = 3.4e38f;
        #pragma unroll
        for (int reg = 0; reg < 16; ++reg) {
            const int row = (reg & 3) + 8 * (reg >> 2) + 4 * half;
            float d0 = sarr[wv * 64 + row]      - 2.f * acc0[reg] + p2v;
            float d1 = sarr[wv * 64 + 32 + row] - 2.f * acc1[reg] + p2v;
            dmin = fminf(dmin, fminf(d0, d1));
        }
        dmin = fminf(dmin, __shfl_xor(dmin, 32));   // merge the two half-wave row sets
        if (half == 0 && p7 * 32 + m < PN)
            atomicMin(&wsm[b * PN + p7 * 32 + m], (u32)__float_as_uint(fmaxf(dmin, 0.f)));
    }
}

// K2: one block per batch; sole writer of d_out (f32: [0:320) logits, [320:6720) md).
__global__ void __launch_bounds__(256) k_head(const u32* __restrict__ wsm,
                                              const float* __restrict__ lw,
                                              float* __restrict__ out) {
    __shared__ float as_[PN];
    const int b = blockIdx.x, t = threadIdx.x;
    if (t < PN) {
        float md = __uint_as_float(wsm[b * PN + t]);
        md = fminf(fmaxf(md, 0.f), 2000.f);
        if (!(md == md)) md = 0.f;
        out[MD0 + b * PN + t] = md;
        as_[t] = logf((md + 1.f) / (md + EPSV));
    }
    __syncthreads();
    if (t < NCLS) {
        float sum = 0.f;
        #pragma unroll 1
        for (int p = 0; p < PN; ++p) sum += as_[p] * lw[t * PN + p];
        sum = fminf(fmaxf(sum, -100.f), 100.f);
        if (!(sum == sum)) sum = 0.f;
        out[b * NCLS + t] = sum;
    }
}

extern "C" void kernel_launch(void* const* d_in, const int* in_sizes, int n_in,
                              void* d_out, int out_size, void* d_ws, size_t ws_size,
                              hipStream_t stream) {
    // Inputs are FLOAT32. Resolve by unique element count (order-proof).
    const float* x  = 0;   // 32*16*8192 = 4194304
    const float* we = 0;   // 64*16*3    = 3072
    const float* wa = 0;   // 64*64*1    = 4096
    const float* pt = 0;   // 200*64*16  = 204800
    const float* lw = 0;   // 10*200     = 2000
    for (int i = 0; i < n_in; ++i) {
        switch (in_sizes[i]) {
            case 4194304: x  = (const float*)d_in[i]; break;
            case 3072:    we = (const float*)d_in[i]; break;
            case 4096:    wa = (const float*)d_in[i]; break;
            case 204800:  pt = (const float*)d_in[i]; break;
            case 2000:    lw = (const float*)d_in[i]; break;
            default: break;
        }
    }
    if (!x || !we || !wa || !pt || !lw) {
        x  = (const float*)d_in[0];
        we = (const float*)d_in[1];
        wa = (const float*)d_in[2];
        pt = (const float*)d_in[3];
        lw = (const float*)d_in[4];
    }
    float* out = (float*)d_out;            // f32: [0:320) logits, [320:6720) min_distances
    u32*   wsm = (u32*)d_ws;               // 6400 u32
    float* p2g = (float*)d_ws + B_ * PN;   // 224 f32
    float* waT = (float*)d_ws + B_ * PN + 224;            // 4096 f32
    u16*   pk  = (u16*)((float*)d_ws + B_ * PN + 224 + LAT * LAT);  // 458752 bf16 (16B-aligned)
    // total workspace use: 42880 B + 917504 B ~= 0.92 MB

    k_init<<<dim3(64), dim3(256), 0, stream>>>(pt, wa, wsm, p2g, waT, pk);
    k_dist<<<dim3(32, 32), dim3(256), 0, stream>>>(x, we, waT, pk, wsm, p2g);
    k_head<<<dim3(B_), dim3(256), 0, stream>>>(wsm, lw, out);
}